// Round 11
// baseline (697.454 us; speedup 1.0000x reference)
//
#include <hip/hip_runtime.h>
#include <hip/hip_fp16.h>

#define FIN 16
#define HH 64
#define BKT_SHIFT 9          // 512 nodes per bucket
#define BSZ (1 << BKT_SHIFT)
#define MAXBUCK 256          // supports N up to 131072
#define NBLK 128             // bincount/binwrite blocks (must match launches)

static constexpr float LN_EPS = 1e-5f;

__device__ __forceinline__ float laneval(float v, int l) {
  return __uint_as_float(__builtin_amdgcn_readlane(__float_as_uint(v), l));
}
__device__ __forceinline__ int rfl(int v) { return __builtin_amdgcn_readfirstlane(v); }
__device__ __forceinline__ float rflf(float v) {
  return __uint_as_float(__builtin_amdgcn_readfirstlane(__float_as_uint(v)));
}

// ---- edge dtype detection: int64 edge_index has all-zero high words ----
__global__ void k_detect(const unsigned int* ei, int E, int* flag) {
  int lane = threadIdx.x & 63;
  int n = (E < 64) ? E : 64;
  unsigned int hi = (lane < n) ? ei[2 * lane + 1] : 0u;
  unsigned long long nz = __ballot(hi != 0u);
  if (lane == 0) *flag = (nz == 0ull) ? 1 : 0;
}

// ==== CSR build via multisplit (write-local, no global atomics) ====
// Round-7: atomic scatter was write-amplification-bound (107MB HBM writes
// for a 6.4MB array). Round-8: k_hist+scan1/2/3 were redundant — per-node
// offsets/inv_deg are now derived inside k_binscatter from the bucket's own
// ebuf slice (count -> LDS scan -> scatter), killing 5 dispatches.

// pass 0: count matrix C[bucket][block]
__global__ __launch_bounds__(256) void k_bincount(const void* ei, int E,
                                                  const int* __restrict__ flag,
                                                  int* __restrict__ Cmat, int nbuck) {
  __shared__ int lh[MAXBUCK];
  const int is64 = *flag;
  int t = threadIdx.x, j = blockIdx.x;
  for (int b = t; b < nbuck; b += 256) lh[b] = 0;
  __syncthreads();
  int chunk = (E + gridDim.x - 1) / gridDim.x;
  int e0 = j * chunk, e1 = (e0 + chunk < E) ? (e0 + chunk) : E;
  for (int e = e0 + t; e < e1; e += 256) {
    int d = is64 ? (int)((const long long*)ei)[E + e] : ((const int*)ei)[E + e];
    atomicAdd(&lh[d >> BKT_SHIFT], 1);
  }
  __syncthreads();
  for (int b = t; b < nbuck; b += 256) Cmat[b * gridDim.x + j] = lh[b];
}

// exclusive scan of Cmat (bucket-major): scanned values ARE absolute ebuf
// cursors, and Cmat[b*NBLK] is bucket b's base in ebuf.
__global__ void k_scanC(int* __restrict__ C, int len) {
  __shared__ int sm[1024];
  __shared__ int carry;
  int t = threadIdx.x;
  if (t == 0) carry = 0;
  __syncthreads();
  for (int base = 0; base < len; base += 1024) {
    int i = base + t;
    int v = (i < len) ? C[i] : 0;
    sm[t] = v;
    __syncthreads();
    for (int off = 1; off < 1024; off <<= 1) {
      int x = (t >= off) ? sm[t - off] : 0;
      __syncthreads();
      sm[t] += x;
      __syncthreads();
    }
    if (i < len) C[i] = carry + sm[t] - v;  // exclusive
    __syncthreads();
    if (t == 0) carry += sm[1023];
    __syncthreads();
  }
}

// pass 1: write (d,s) packed into ebuf at private per-(block,bucket) cursors
__global__ __launch_bounds__(256) void k_binwrite(const void* ei, int E,
                                                  const int* __restrict__ flag,
                                                  const int* __restrict__ Cmat,
                                                  unsigned long long* __restrict__ ebuf,
                                                  int nbuck) {
  __shared__ int lcur[MAXBUCK];
  const int is64 = *flag;
  int t = threadIdx.x, j = blockIdx.x;
  for (int b = t; b < nbuck; b += 256) lcur[b] = Cmat[b * gridDim.x + j];
  __syncthreads();
  int chunk = (E + gridDim.x - 1) / gridDim.x;
  int e0 = j * chunk, e1 = (e0 + chunk < E) ? (e0 + chunk) : E;
  for (int e = e0 + t; e < e1; e += 256) {
    int s, d;
    if (is64) {
      const long long* p = (const long long*)ei;
      s = (int)p[e];
      d = (int)p[E + e];
    } else {
      const int* p = (const int*)ei;
      s = p[e];
      d = p[E + e];
    }
    int pos = atomicAdd(&lcur[d >> BKT_SHIFT], 1);
    ebuf[pos] = ((unsigned long long)(unsigned)d << 32) | (unsigned)s;
  }
}

// pass 2: one block per bucket. Derives per-node counts from the bucket's
// ebuf slice (LDS histogram), LDS-scans them into offsets/inv_deg, then
// scatters csr within the bucket's contiguous region (single-CU locality).
__global__ __launch_bounds__(256) void k_binscatter(
    const unsigned long long* __restrict__ ebuf, const int* __restrict__ Cs,
    int E, int N, int nbuck, int* __restrict__ offsets,
    float* __restrict__ inv_deg, int* __restrict__ csr) {
  __shared__ int cnt[BSZ];
  __shared__ int sm[256];
  int b = blockIdx.x, t = threadIdx.x;
  int n0 = b << BKT_SHIFT;
  int nn = N - n0;
  if (nn > BSZ) nn = BSZ;
  int p0 = Cs[b * NBLK];
  int p1 = (b + 1 < nbuck) ? Cs[(b + 1) * NBLK] : E;

  for (int i = t; i < BSZ; i += 256) cnt[i] = 0;
  __syncthreads();
  // count per node
  for (int p = p0 + t; p < p1; p += 256) {
    int d = (int)(ebuf[p] >> 32);
    atomicAdd(&cnt[d - n0], 1);
  }
  __syncthreads();
  // exclusive scan of 512 counts: thread t owns pair (2t, 2t+1)
  int c0 = cnt[2 * t], c1 = cnt[2 * t + 1];
  int ps = c0 + c1;
  sm[t] = ps;
  __syncthreads();
  for (int off = 1; off < 256; off <<= 1) {
    int x = (t >= off) ? sm[t - off] : 0;
    __syncthreads();
    sm[t] += x;
    __syncthreads();
  }
  int excl = sm[t] - ps;  // exclusive over pairs
  cnt[2 * t] = excl;
  cnt[2 * t + 1] = excl + c0;
  if (2 * t < nn) {
    offsets[n0 + 2 * t] = p0 + excl;
    inv_deg[n0 + 2 * t] = (c0 > 0) ? (1.0f / (float)c0) : 0.0f;
  }
  if (2 * t + 1 < nn) {
    offsets[n0 + 2 * t + 1] = p0 + excl + c0;
    inv_deg[n0 + 2 * t + 1] = (c1 > 0) ? (1.0f / (float)c1) : 0.0f;
  }
  if (b == nbuck - 1 && t == 0) offsets[N] = E;
  __syncthreads();
  // scatter: cnt[] now holds local exclusive offsets, used as cursors
  for (int p = p0 + t; p < p1; p += 256) {
    unsigned long long pk = ebuf[p];
    int d = (int)(pk >> 32);
    int s = (int)(pk & 0xffffffffull);
    int pos = p0 + atomicAdd(&cnt[d - n0], 1);
    csr[pos] = s;
  }
}

// ---- input projection: h = relu(x @ Wp^T + bp), one wave per node ----
__global__ __launch_bounds__(256) void k_inproj(const float* __restrict__ x,
                                                const float* __restrict__ Wp,
                                                const float* __restrict__ bp,
                                                float* __restrict__ h,
                                                __half* __restrict__ h16, int N) {
  int lane = threadIdx.x & 63;
  int wid = (blockIdx.x * blockDim.x + threadIdx.x) >> 6;
  int nwaves = (gridDim.x * blockDim.x) >> 6;
  float w[FIN];
#pragma unroll
  for (int k = 0; k < FIN; ++k) w[k] = Wp[lane * FIN + k];
  float b = bp[lane];
  for (int n = wid; n < N; n += nwaves) {
    const float4* xr = (const float4*)(x + (size_t)n * FIN);
    float a0 = b, a1 = 0.f;
#pragma unroll
    for (int q = 0; q < FIN / 4; ++q) {
      float4 xv = xr[q];
      a0 = fmaf(xv.x, w[4 * q + 0], a0);
      a1 = fmaf(xv.y, w[4 * q + 1], a1);
      a0 = fmaf(xv.z, w[4 * q + 2], a0);
      a1 = fmaf(xv.w, w[4 * q + 3], a1);
    }
    float r = fmaxf(a0 + a1, 0.0f);
    h[(size_t)n * HH + lane] = r;
    h16[(size_t)n * HH + lane] = __float2half(r);
  }
}

// ---- neighbor-mean gather ONLY: agg16[n] = mean of h16 rows ----
__global__ __launch_bounds__(256, 8) void k_gather(
    const __half* __restrict__ h16_in, const int* __restrict__ offsets,
    const int* __restrict__ csr, const float* __restrict__ inv_deg,
    __half* __restrict__ agg16, int N) {
  int lane = threadIdx.x & 63;
  int wid = (blockIdx.x * blockDim.x + threadIdx.x) >> 6;
  int nwaves = (gridDim.x * blockDim.x) >> 6;
  for (int n = wid; n < N; n += nwaves) {
    int p0 = rfl(offsets[n]);
    int p1 = rfl(offsets[n + 1]);
    float idg = rflf(inv_deg[n]);
    float a0 = 0.f, a1 = 0.f, a2 = 0.f, a3 = 0.f;
    int p = p0;
    for (; p + 16 <= p1; p += 16) {
      float v[16];
#pragma unroll
      for (int i = 0; i < 16; ++i) {
        int s = rfl(csr[p + i]);
        v[i] = __half2float(h16_in[(size_t)s * HH + lane]);
      }
      a0 += (v[0] + v[1]) + (v[2] + v[3]);
      a1 += (v[4] + v[5]) + (v[6] + v[7]);
      a2 += (v[8] + v[9]) + (v[10] + v[11]);
      a3 += (v[12] + v[13]) + (v[14] + v[15]);
    }
    for (; p + 4 <= p1; p += 4) {
      int s0 = rfl(csr[p + 0]), s1 = rfl(csr[p + 1]);
      int s2 = rfl(csr[p + 2]), s3 = rfl(csr[p + 3]);
      float v0 = __half2float(h16_in[(size_t)s0 * HH + lane]);
      float v1 = __half2float(h16_in[(size_t)s1 * HH + lane]);
      float v2 = __half2float(h16_in[(size_t)s2 * HH + lane]);
      float v3 = __half2float(h16_in[(size_t)s3 * HH + lane]);
      a0 += (v0 + v1) + (v2 + v3);
    }
    for (; p < p1; ++p) {
      int s = rfl(csr[p]);
      a0 += __half2float(h16_in[(size_t)s * HH + lane]);
    }
    agg16[(size_t)n * HH + lane] = __float2half(((a0 + a1) + (a2 + a3)) * idg);
  }
}

// ---- GEMV x2 + LayerNorm + relu + residual, 4 nodes per wave ----
// Round-8: 66µs at occupancy 25% / VALU 54% = latency-bound. Fix: 2048
// blocks (2x resident waves) + NB=4 node ILP (8 indep FMA chains per
// weight load); launch_bounds(256,4) caps VGPR at 128.
__global__ __launch_bounds__(256, 4) void k_gemv(
    const float* __restrict__ h_in, const __half* __restrict__ agg16,
    float* __restrict__ h_out, __half* __restrict__ h16_out,
    const float* __restrict__ Wl, const float* __restrict__ bl,
    const float* __restrict__ Wr, const float* __restrict__ gamma,
    const float* __restrict__ beta, int N) {
  int lane = threadIdx.x & 63;
  int wid = (blockIdx.x * blockDim.x + threadIdx.x) >> 6;
  int nwaves = (gridDim.x * blockDim.x) >> 6;
  float blv = bl[lane], g = gamma[lane], be = beta[lane];
  const float4* wlr = (const float4*)(Wl + lane * HH);
  const float4* wrr = (const float4*)(Wr + lane * HH);

  for (int n = 4 * wid; n < N; n += 4 * nwaves) {
    int m0 = n;
    int m1 = (n + 1 < N) ? n + 1 : N - 1;
    int m2 = (n + 2 < N) ? n + 2 : N - 1;
    int m3 = (n + 3 < N) ? n + 3 : N - 1;
    float hn0 = h_in[(size_t)m0 * HH + lane];
    float hn1 = h_in[(size_t)m1 * HH + lane];
    float hn2 = h_in[(size_t)m2 * HH + lane];
    float hn3 = h_in[(size_t)m3 * HH + lane];
    float ac0 = __half2float(agg16[(size_t)m0 * HH + lane]);
    float ac1 = __half2float(agg16[(size_t)m1 * HH + lane]);
    float ac2 = __half2float(agg16[(size_t)m2 * HH + lane]);
    float ac3 = __half2float(agg16[(size_t)m3 * HH + lane]);

    float ol0 = blv, ol1 = blv, ol2 = blv, ol3 = blv;
    float or0 = 0.f, or1 = 0.f, or2 = 0.f, or3 = 0.f;
#pragma unroll
    for (int q = 0; q < HH / 4; ++q) {
      float4 wl4 = wlr[q];
      float4 wr4 = wrr[q];
#pragma unroll
      for (int u = 0; u < 4; ++u) {
        int k = 4 * q + u;
        float wlk = (u == 0) ? wl4.x : (u == 1) ? wl4.y : (u == 2) ? wl4.z : wl4.w;
        float wrk = (u == 0) ? wr4.x : (u == 1) ? wr4.y : (u == 2) ? wr4.z : wr4.w;
        ol0 = fmaf(laneval(ac0, k), wlk, ol0);
        ol1 = fmaf(laneval(ac1, k), wlk, ol1);
        ol2 = fmaf(laneval(ac2, k), wlk, ol2);
        ol3 = fmaf(laneval(ac3, k), wlk, ol3);
        or0 = fmaf(laneval(hn0, k), wrk, or0);
        or1 = fmaf(laneval(hn1, k), wrk, or1);
        or2 = fmaf(laneval(hn2, k), wrk, or2);
        or3 = fmaf(laneval(hn3, k), wrk, or3);
      }
    }

#pragma unroll
    for (int b = 0; b < 4; ++b) {
      float out = (b == 0) ? (ol0 + or0) : (b == 1) ? (ol1 + or1)
                : (b == 2) ? (ol2 + or2) : (ol3 + or3);
      float hn = (b == 0) ? hn0 : (b == 1) ? hn1 : (b == 2) ? hn2 : hn3;
      int m = (b == 0) ? m0 : (b == 1) ? m1 : (b == 2) ? m2 : m3;
      float s = out;
#pragma unroll
      for (int msk = 1; msk < 64; msk <<= 1) s += __shfl_xor(s, msk);
      float mu = s * (1.0f / 64.0f);
      float d = out - mu;
      float vs = d * d;
#pragma unroll
      for (int msk = 1; msk < 64; msk <<= 1) vs += __shfl_xor(vs, msk);
      float var = vs * (1.0f / 64.0f);
      float val = fmaf(d * rsqrtf(var + LN_EPS), g, be);
      float res = fmaxf(val, 0.0f) + hn;
      h_out[(size_t)m * HH + lane] = res;
      h16_out[(size_t)m * HH + lane] = __float2half(res);
    }
  }
}

// ---- MLP head: y = relu(h@W1^T + b1) @ W2^T + b2 ; 2 nodes per wave ----
__global__ __launch_bounds__(256) void k_mlp(const float* __restrict__ h,
                                             const float* __restrict__ W1,
                                             const float* __restrict__ b1,
                                             const float* __restrict__ W2,
                                             const float* __restrict__ b2,
                                             float* __restrict__ y, int N) {
  int lane = threadIdx.x & 63;
  int half = lane >> 5;
  int j = lane & 31;
  int wid = (blockIdx.x * blockDim.x + threadIdx.x) >> 6;
  int nwaves = (gridDim.x * blockDim.x) >> 6;

  float w1[HH];
#pragma unroll
  for (int k = 0; k < HH; ++k) w1[k] = W1[j * HH + k];
  float b1v = b1[j], w2v = W2[j], b2v = b2[0];

  for (int base = wid * 2; base < N; base += nwaves * 2) {
    int n = base + half;
    float t0 = b1v, t1 = 0.0f;
    if (n < N) {
      const float4* hr = (const float4*)(h + (size_t)n * HH);
#pragma unroll
      for (int q = 0; q < HH / 4; ++q) {
        float4 hv = hr[q];
        t0 = fmaf(hv.x, w1[4 * q + 0], t0);
        t1 = fmaf(hv.y, w1[4 * q + 1], t1);
        t0 = fmaf(hv.z, w1[4 * q + 2], t0);
        t1 = fmaf(hv.w, w1[4 * q + 3], t1);
      }
    }
    float t = fmaxf(t0 + t1, 0.0f) * w2v;
#pragma unroll
    for (int m = 1; m < 32; m <<= 1) t += __shfl_xor(t, m);  // stays in half
    if (j == 0 && n < N) y[n] = t + b2v;
  }
}

extern "C" void kernel_launch(void* const* d_in, const int* in_sizes, int n_in,
                              void* d_out, int out_size, void* d_ws, size_t ws_size,
                              hipStream_t stream) {
  const float* x = (const float*)d_in[0];
  const void* ei = d_in[1];
  const float* Wp = (const float*)d_in[2];
  const float* bp = (const float*)d_in[3];
  const float* Wl = (const float*)d_in[4];
  const float* bl = (const float*)d_in[5];
  const float* Wr = (const float*)d_in[6];
  const float* gamma = (const float*)d_in[7];
  const float* beta = (const float*)d_in[8];
  const float* W1 = (const float*)d_in[9];
  const float* b1 = (const float*)d_in[10];
  const float* W2 = (const float*)d_in[11];
  const float* b2 = (const float*)d_in[12];
  float* y = (float*)d_out;

  const int N = in_sizes[0] / FIN;
  const int E = in_sizes[1] / 2;
  const int nbuck = (N + BSZ - 1) >> BKT_SHIFT;  // <= MAXBUCK

  // workspace carve (256B aligned chunks)
  char* w = (char*)d_ws;
  auto carve = [&](size_t bytes) -> char* {
    char* p = w;
    w += (bytes + 255) / 256 * 256;
    return p;
  };
  int* offsets = (int*)carve(((size_t)N + 1) * 4);
  int* flag = (int*)carve(4);
  float* invdeg = (float*)carve((size_t)N * 4);
  int* csr = (int*)carve((size_t)E * 4);
  int* Cmat = (int*)carve((size_t)MAXBUCK * NBLK * 4);
  unsigned long long* ebuf = (unsigned long long*)carve((size_t)E * 8);
  float* hA = (float*)carve((size_t)N * HH * 4);
  float* hB = (float*)carve((size_t)N * HH * 4);
  __half* h16A = (__half*)carve((size_t)N * HH * 2);
  __half* h16B = (__half*)carve((size_t)N * HH * 2);
  __half* agg16 = (__half*)carve((size_t)N * HH * 2);  // reused both layers

  k_detect<<<1, 64, 0, stream>>>((const unsigned int*)ei, E, flag);
  // CSR build: multisplit; binscatter also derives offsets/inv_deg
  k_bincount<<<NBLK, 256, 0, stream>>>(ei, E, flag, Cmat, nbuck);
  k_scanC<<<1, 1024, 0, stream>>>(Cmat, nbuck * NBLK);
  k_binwrite<<<NBLK, 256, 0, stream>>>(ei, E, flag, Cmat, ebuf, nbuck);
  k_binscatter<<<nbuck, 256, 0, stream>>>(ebuf, Cmat, E, N, nbuck,
                                          offsets, invdeg, csr);
  k_inproj<<<1024, 256, 0, stream>>>(x, Wp, bp, hA, h16A, N);
  // layer 0
  k_gather<<<2048, 256, 0, stream>>>(h16A, offsets, csr, invdeg, agg16, N);
  k_gemv<<<2048, 256, 0, stream>>>(hA, agg16, hB, h16B,
                                   Wl, bl, Wr, gamma, beta, N);
  // layer 1
  k_gather<<<2048, 256, 0, stream>>>(h16B, offsets, csr, invdeg, agg16, N);
  k_gemv<<<2048, 256, 0, stream>>>(hB, agg16, hA, h16A,
                                   Wl + HH * HH, bl + HH, Wr + HH * HH,
                                   gamma + HH, beta + HH, N);
  k_mlp<<<512, 256, 0, stream>>>(hA, W1, b1, W2, b2, y, N);
}

// Round 12
// 450.510 us; speedup vs baseline: 1.5481x; 1.5481x over previous
//
#include <hip/hip_runtime.h>
#include <hip/hip_fp16.h>

#define FIN 16
#define HH 64
#define BKT_SHIFT 9          // 512 nodes per bucket
#define BSZ (1 << BKT_SHIFT)
#define MAXBUCK 256          // supports N up to 131072
#define NBLK 128             // bincount/binwrite blocks (must match launches)

static constexpr float LN_EPS = 1e-5f;

__device__ __forceinline__ float laneval(float v, int l) {
  return __uint_as_float(__builtin_amdgcn_readlane(__float_as_uint(v), l));
}
__device__ __forceinline__ int rfl(int v) { return __builtin_amdgcn_readfirstlane(v); }
__device__ __forceinline__ float rflf(float v) {
  return __uint_as_float(__builtin_amdgcn_readfirstlane(__float_as_uint(v)));
}

// ---- edge dtype detection: int64 edge_index has all-zero high words ----
__global__ void k_detect(const unsigned int* ei, int E, int* flag) {
  int lane = threadIdx.x & 63;
  int n = (E < 64) ? E : 64;
  unsigned int hi = (lane < n) ? ei[2 * lane + 1] : 0u;
  unsigned long long nz = __ballot(hi != 0u);
  if (lane == 0) *flag = (nz == 0ull) ? 1 : 0;
}

// ==== CSR build via multisplit (write-local, no global atomics) ====
// Round-7: atomic scatter was write-amplification-bound (107MB HBM writes
// for a 6.4MB array). Round-8 fusion (offsets/inv_deg derived inside
// k_binscatter) measured ~60us cheaper than the k_hist+scan chain — keep.

// pass 0: count matrix C[bucket][block]
__global__ __launch_bounds__(256) void k_bincount(const void* ei, int E,
                                                  const int* __restrict__ flag,
                                                  int* __restrict__ Cmat, int nbuck) {
  __shared__ int lh[MAXBUCK];
  const int is64 = *flag;
  int t = threadIdx.x, j = blockIdx.x;
  for (int b = t; b < nbuck; b += 256) lh[b] = 0;
  __syncthreads();
  int chunk = (E + gridDim.x - 1) / gridDim.x;
  int e0 = j * chunk, e1 = (e0 + chunk < E) ? (e0 + chunk) : E;
  for (int e = e0 + t; e < e1; e += 256) {
    int d = is64 ? (int)((const long long*)ei)[E + e] : ((const int*)ei)[E + e];
    atomicAdd(&lh[d >> BKT_SHIFT], 1);
  }
  __syncthreads();
  for (int b = t; b < nbuck; b += 256) Cmat[b * gridDim.x + j] = lh[b];
}

// exclusive scan of Cmat (bucket-major): scanned values ARE absolute ebuf
// cursors, and Cmat[b*NBLK] is bucket b's base in ebuf.
__global__ void k_scanC(int* __restrict__ C, int len) {
  __shared__ int sm[1024];
  __shared__ int carry;
  int t = threadIdx.x;
  if (t == 0) carry = 0;
  __syncthreads();
  for (int base = 0; base < len; base += 1024) {
    int i = base + t;
    int v = (i < len) ? C[i] : 0;
    sm[t] = v;
    __syncthreads();
    for (int off = 1; off < 1024; off <<= 1) {
      int x = (t >= off) ? sm[t - off] : 0;
      __syncthreads();
      sm[t] += x;
      __syncthreads();
    }
    if (i < len) C[i] = carry + sm[t] - v;  // exclusive
    __syncthreads();
    if (t == 0) carry += sm[1023];
    __syncthreads();
  }
}

// pass 1: write (d,s) packed into ebuf at private per-(block,bucket) cursors
__global__ __launch_bounds__(256) void k_binwrite(const void* ei, int E,
                                                  const int* __restrict__ flag,
                                                  const int* __restrict__ Cmat,
                                                  unsigned long long* __restrict__ ebuf,
                                                  int nbuck) {
  __shared__ int lcur[MAXBUCK];
  const int is64 = *flag;
  int t = threadIdx.x, j = blockIdx.x;
  for (int b = t; b < nbuck; b += 256) lcur[b] = Cmat[b * gridDim.x + j];
  __syncthreads();
  int chunk = (E + gridDim.x - 1) / gridDim.x;
  int e0 = j * chunk, e1 = (e0 + chunk < E) ? (e0 + chunk) : E;
  for (int e = e0 + t; e < e1; e += 256) {
    int s, d;
    if (is64) {
      const long long* p = (const long long*)ei;
      s = (int)p[e];
      d = (int)p[E + e];
    } else {
      const int* p = (const int*)ei;
      s = p[e];
      d = p[E + e];
    }
    int pos = atomicAdd(&lcur[d >> BKT_SHIFT], 1);
    ebuf[pos] = ((unsigned long long)(unsigned)d << 32) | (unsigned)s;
  }
}

// pass 2: one block per bucket. Derives per-node counts from the bucket's
// ebuf slice (LDS histogram), LDS-scans them into offsets/inv_deg, then
// scatters csr within the bucket's contiguous region (single-CU locality).
__global__ __launch_bounds__(256) void k_binscatter(
    const unsigned long long* __restrict__ ebuf, const int* __restrict__ Cs,
    int E, int N, int nbuck, int* __restrict__ offsets,
    float* __restrict__ inv_deg, int* __restrict__ csr) {
  __shared__ int cnt[BSZ];
  __shared__ int sm[256];
  int b = blockIdx.x, t = threadIdx.x;
  int n0 = b << BKT_SHIFT;
  int nn = N - n0;
  if (nn > BSZ) nn = BSZ;
  int p0 = Cs[b * NBLK];
  int p1 = (b + 1 < nbuck) ? Cs[(b + 1) * NBLK] : E;

  for (int i = t; i < BSZ; i += 256) cnt[i] = 0;
  __syncthreads();
  // count per node
  for (int p = p0 + t; p < p1; p += 256) {
    int d = (int)(ebuf[p] >> 32);
    atomicAdd(&cnt[d - n0], 1);
  }
  __syncthreads();
  // exclusive scan of 512 counts: thread t owns pair (2t, 2t+1)
  int c0 = cnt[2 * t], c1 = cnt[2 * t + 1];
  int ps = c0 + c1;
  sm[t] = ps;
  __syncthreads();
  for (int off = 1; off < 256; off <<= 1) {
    int x = (t >= off) ? sm[t - off] : 0;
    __syncthreads();
    sm[t] += x;
    __syncthreads();
  }
  int excl = sm[t] - ps;  // exclusive over pairs
  cnt[2 * t] = excl;
  cnt[2 * t + 1] = excl + c0;
  if (2 * t < nn) {
    offsets[n0 + 2 * t] = p0 + excl;
    inv_deg[n0 + 2 * t] = (c0 > 0) ? (1.0f / (float)c0) : 0.0f;
  }
  if (2 * t + 1 < nn) {
    offsets[n0 + 2 * t + 1] = p0 + excl + c0;
    inv_deg[n0 + 2 * t + 1] = (c1 > 0) ? (1.0f / (float)c1) : 0.0f;
  }
  if (b == nbuck - 1 && t == 0) offsets[N] = E;
  __syncthreads();
  // scatter: cnt[] now holds local exclusive offsets, used as cursors
  for (int p = p0 + t; p < p1; p += 256) {
    unsigned long long pk = ebuf[p];
    int d = (int)(pk >> 32);
    int s = (int)(pk & 0xffffffffull);
    int pos = p0 + atomicAdd(&cnt[d - n0], 1);
    csr[pos] = s;
  }
}

// ---- input projection: h = relu(x @ Wp^T + bp), one wave per node ----
__global__ __launch_bounds__(256) void k_inproj(const float* __restrict__ x,
                                                const float* __restrict__ Wp,
                                                const float* __restrict__ bp,
                                                float* __restrict__ h,
                                                __half* __restrict__ h16, int N) {
  int lane = threadIdx.x & 63;
  int wid = (blockIdx.x * blockDim.x + threadIdx.x) >> 6;
  int nwaves = (gridDim.x * blockDim.x) >> 6;
  float w[FIN];
#pragma unroll
  for (int k = 0; k < FIN; ++k) w[k] = Wp[lane * FIN + k];
  float b = bp[lane];
  for (int n = wid; n < N; n += nwaves) {
    const float4* xr = (const float4*)(x + (size_t)n * FIN);
    float a0 = b, a1 = 0.f;
#pragma unroll
    for (int q = 0; q < FIN / 4; ++q) {
      float4 xv = xr[q];
      a0 = fmaf(xv.x, w[4 * q + 0], a0);
      a1 = fmaf(xv.y, w[4 * q + 1], a1);
      a0 = fmaf(xv.z, w[4 * q + 2], a0);
      a1 = fmaf(xv.w, w[4 * q + 3], a1);
    }
    float r = fmaxf(a0 + a1, 0.0f);
    h[(size_t)n * HH + lane] = r;
    h16[(size_t)n * HH + lane] = __float2half(r);
  }
}

// ---- neighbor-mean gather ONLY: agg16[n] = mean of h16 rows ----
__global__ __launch_bounds__(256, 8) void k_gather(
    const __half* __restrict__ h16_in, const int* __restrict__ offsets,
    const int* __restrict__ csr, const float* __restrict__ inv_deg,
    __half* __restrict__ agg16, int N) {
  int lane = threadIdx.x & 63;
  int wid = (blockIdx.x * blockDim.x + threadIdx.x) >> 6;
  int nwaves = (gridDim.x * blockDim.x) >> 6;
  for (int n = wid; n < N; n += nwaves) {
    int p0 = rfl(offsets[n]);
    int p1 = rfl(offsets[n + 1]);
    float idg = rflf(inv_deg[n]);
    float a0 = 0.f, a1 = 0.f, a2 = 0.f, a3 = 0.f;
    int p = p0;
    for (; p + 16 <= p1; p += 16) {
      float v[16];
#pragma unroll
      for (int i = 0; i < 16; ++i) {
        int s = rfl(csr[p + i]);
        v[i] = __half2float(h16_in[(size_t)s * HH + lane]);
      }
      a0 += (v[0] + v[1]) + (v[2] + v[3]);
      a1 += (v[4] + v[5]) + (v[6] + v[7]);
      a2 += (v[8] + v[9]) + (v[10] + v[11]);
      a3 += (v[12] + v[13]) + (v[14] + v[15]);
    }
    for (; p + 4 <= p1; p += 4) {
      int s0 = rfl(csr[p + 0]), s1 = rfl(csr[p + 1]);
      int s2 = rfl(csr[p + 2]), s3 = rfl(csr[p + 3]);
      float v0 = __half2float(h16_in[(size_t)s0 * HH + lane]);
      float v1 = __half2float(h16_in[(size_t)s1 * HH + lane]);
      float v2 = __half2float(h16_in[(size_t)s2 * HH + lane]);
      float v3 = __half2float(h16_in[(size_t)s3 * HH + lane]);
      a0 += (v0 + v1) + (v2 + v3);
    }
    for (; p < p1; ++p) {
      int s = rfl(csr[p]);
      a0 += __half2float(h16_in[(size_t)s * HH + lane]);
    }
    agg16[(size_t)n * HH + lane] = __float2half(((a0 + a1) + (a2 + a3)) * idg);
  }
}

// ---- GEMV x2 + LayerNorm + relu + residual, 2 nodes per wave ----
// Round-11 post-mortem: NB=4 + __launch_bounds__(256,4) made the compiler
// allocate only 64 VGPRs -> working set spilled to scratch (FETCH 381MB,
// WRITE 203MB, 190us). REVERTED to the measured round-8 shape: NB=2, plain
// launch_bounds(256), VGPR=84, no spills, 66us. Do NOT pair occupancy
// requests with larger working sets on this compiler.
__global__ __launch_bounds__(256) void k_gemv(
    const float* __restrict__ h_in, const __half* __restrict__ agg16,
    float* __restrict__ h_out, __half* __restrict__ h16_out,
    const float* __restrict__ Wl, const float* __restrict__ bl,
    const float* __restrict__ Wr, const float* __restrict__ gamma,
    const float* __restrict__ beta, int N) {
  int lane = threadIdx.x & 63;
  int wid = (blockIdx.x * blockDim.x + threadIdx.x) >> 6;
  int nwaves = (gridDim.x * blockDim.x) >> 6;
  float blv = bl[lane], g = gamma[lane], be = beta[lane];
  const float4* wlr = (const float4*)(Wl + lane * HH);
  const float4* wrr = (const float4*)(Wr + lane * HH);

  for (int n = 2 * wid; n < N; n += 2 * nwaves) {
    int m2 = (n + 1 < N) ? (n + 1) : n;  // tail duplicates own node (benign)
    float hnA = h_in[(size_t)n * HH + lane];
    float hnB = h_in[(size_t)m2 * HH + lane];
    float acA = __half2float(agg16[(size_t)n * HH + lane]);
    float acB = __half2float(agg16[(size_t)m2 * HH + lane]);

    float olA = blv, orA = 0.f, olB = blv, orB = 0.f;
#pragma unroll
    for (int q = 0; q < HH / 4; ++q) {
      float4 wl4 = wlr[q];
      float4 wr4 = wrr[q];
      olA = fmaf(laneval(acA, 4 * q + 0), wl4.x, olA);
      olB = fmaf(laneval(acB, 4 * q + 0), wl4.x, olB);
      orA = fmaf(laneval(hnA, 4 * q + 0), wr4.x, orA);
      orB = fmaf(laneval(hnB, 4 * q + 0), wr4.x, orB);
      olA = fmaf(laneval(acA, 4 * q + 1), wl4.y, olA);
      olB = fmaf(laneval(acB, 4 * q + 1), wl4.y, olB);
      orA = fmaf(laneval(hnA, 4 * q + 1), wr4.y, orA);
      orB = fmaf(laneval(hnB, 4 * q + 1), wr4.y, orB);
      olA = fmaf(laneval(acA, 4 * q + 2), wl4.z, olA);
      olB = fmaf(laneval(acB, 4 * q + 2), wl4.z, olB);
      orA = fmaf(laneval(hnA, 4 * q + 2), wr4.z, orA);
      orB = fmaf(laneval(hnB, 4 * q + 2), wr4.z, orB);
      olA = fmaf(laneval(acA, 4 * q + 3), wl4.w, olA);
      olB = fmaf(laneval(acB, 4 * q + 3), wl4.w, olB);
      orA = fmaf(laneval(hnA, 4 * q + 3), wr4.w, orA);
      orB = fmaf(laneval(hnB, 4 * q + 3), wr4.w, orB);
    }

#pragma unroll
    for (int b = 0; b < 2; ++b) {
      float out = (b == 0) ? (olA + orA) : (olB + orB);
      float hn = (b == 0) ? hnA : hnB;
      int m = (b == 0) ? n : m2;
      float s = out;
#pragma unroll
      for (int msk = 1; msk < 64; msk <<= 1) s += __shfl_xor(s, msk);
      float mu = s * (1.0f / 64.0f);
      float d = out - mu;
      float vs = d * d;
#pragma unroll
      for (int msk = 1; msk < 64; msk <<= 1) vs += __shfl_xor(vs, msk);
      float var = vs * (1.0f / 64.0f);
      float val = fmaf(d * rsqrtf(var + LN_EPS), g, be);
      float res = fmaxf(val, 0.0f) + hn;
      h_out[(size_t)m * HH + lane] = res;
      h16_out[(size_t)m * HH + lane] = __float2half(res);
    }
  }
}

// ---- MLP head: y = relu(h@W1^T + b1) @ W2^T + b2 ; 2 nodes per wave ----
__global__ __launch_bounds__(256) void k_mlp(const float* __restrict__ h,
                                             const float* __restrict__ W1,
                                             const float* __restrict__ b1,
                                             const float* __restrict__ W2,
                                             const float* __restrict__ b2,
                                             float* __restrict__ y, int N) {
  int lane = threadIdx.x & 63;
  int half = lane >> 5;
  int j = lane & 31;
  int wid = (blockIdx.x * blockDim.x + threadIdx.x) >> 6;
  int nwaves = (gridDim.x * blockDim.x) >> 6;

  float w1[HH];
#pragma unroll
  for (int k = 0; k < HH; ++k) w1[k] = W1[j * HH + k];
  float b1v = b1[j], w2v = W2[j], b2v = b2[0];

  for (int base = wid * 2; base < N; base += nwaves * 2) {
    int n = base + half;
    float t0 = b1v, t1 = 0.0f;
    if (n < N) {
      const float4* hr = (const float4*)(h + (size_t)n * HH);
#pragma unroll
      for (int q = 0; q < HH / 4; ++q) {
        float4 hv = hr[q];
        t0 = fmaf(hv.x, w1[4 * q + 0], t0);
        t1 = fmaf(hv.y, w1[4 * q + 1], t1);
        t0 = fmaf(hv.z, w1[4 * q + 2], t0);
        t1 = fmaf(hv.w, w1[4 * q + 3], t1);
      }
    }
    float t = fmaxf(t0 + t1, 0.0f) * w2v;
#pragma unroll
    for (int m = 1; m < 32; m <<= 1) t += __shfl_xor(t, m);  // stays in half
    if (j == 0 && n < N) y[n] = t + b2v;
  }
}

extern "C" void kernel_launch(void* const* d_in, const int* in_sizes, int n_in,
                              void* d_out, int out_size, void* d_ws, size_t ws_size,
                              hipStream_t stream) {
  const float* x = (const float*)d_in[0];
  const void* ei = d_in[1];
  const float* Wp = (const float*)d_in[2];
  const float* bp = (const float*)d_in[3];
  const float* Wl = (const float*)d_in[4];
  const float* bl = (const float*)d_in[5];
  const float* Wr = (const float*)d_in[6];
  const float* gamma = (const float*)d_in[7];
  const float* beta = (const float*)d_in[8];
  const float* W1 = (const float*)d_in[9];
  const float* b1 = (const float*)d_in[10];
  const float* W2 = (const float*)d_in[11];
  const float* b2 = (const float*)d_in[12];
  float* y = (float*)d_out;

  const int N = in_sizes[0] / FIN;
  const int E = in_sizes[1] / 2;
  const int nbuck = (N + BSZ - 1) >> BKT_SHIFT;  // <= MAXBUCK

  // workspace carve (256B aligned chunks)
  char* w = (char*)d_ws;
  auto carve = [&](size_t bytes) -> char* {
    char* p = w;
    w += (bytes + 255) / 256 * 256;
    return p;
  };
  int* offsets = (int*)carve(((size_t)N + 1) * 4);
  int* flag = (int*)carve(4);
  float* invdeg = (float*)carve((size_t)N * 4);
  int* csr = (int*)carve((size_t)E * 4);
  int* Cmat = (int*)carve((size_t)MAXBUCK * NBLK * 4);
  unsigned long long* ebuf = (unsigned long long*)carve((size_t)E * 8);
  float* hA = (float*)carve((size_t)N * HH * 4);
  float* hB = (float*)carve((size_t)N * HH * 4);
  __half* h16A = (__half*)carve((size_t)N * HH * 2);
  __half* h16B = (__half*)carve((size_t)N * HH * 2);
  __half* agg16 = (__half*)carve((size_t)N * HH * 2);  // reused both layers

  k_detect<<<1, 64, 0, stream>>>((const unsigned int*)ei, E, flag);
  // CSR build: multisplit; binscatter also derives offsets/inv_deg
  k_bincount<<<NBLK, 256, 0, stream>>>(ei, E, flag, Cmat, nbuck);
  k_scanC<<<1, 1024, 0, stream>>>(Cmat, nbuck * NBLK);
  k_binwrite<<<NBLK, 256, 0, stream>>>(ei, E, flag, Cmat, ebuf, nbuck);
  k_binscatter<<<nbuck, 256, 0, stream>>>(ebuf, Cmat, E, N, nbuck,
                                          offsets, invdeg, csr);
  k_inproj<<<1024, 256, 0, stream>>>(x, Wp, bp, hA, h16A, N);
  // layer 0
  k_gather<<<2048, 256, 0, stream>>>(h16A, offsets, csr, invdeg, agg16, N);
  k_gemv<<<2048, 256, 0, stream>>>(hA, agg16, hB, h16B,
                                   Wl, bl, Wr, gamma, beta, N);
  // layer 1
  k_gather<<<2048, 256, 0, stream>>>(h16B, offsets, csr, invdeg, agg16, N);
  k_gemv<<<2048, 256, 0, stream>>>(hB, agg16, hA, h16A,
                                   Wl + HH * HH, bl + HH, Wr + HH * HH,
                                   gamma + HH, beta + HH, N);
  k_mlp<<<512, 256, 0, stream>>>(hA, W1, b1, W2, b2, y, N);
}

// Round 14
// 398.200 us; speedup vs baseline: 1.7515x; 1.1314x over previous
//
#include <hip/hip_runtime.h>
#include <hip/hip_fp16.h>

#define FIN 16
#define HH 64
#define BKT_SHIFT 9          // 512 nodes per bucket
#define BSZ (1 << BKT_SHIFT)
#define MAXBUCK 256          // supports N up to 131072
#define NBLK 128             // bincount/binwrite blocks (must match launches)

static constexpr float LN_EPS = 1e-5f;

typedef _Float16 half4v __attribute__((ext_vector_type(4)));
typedef float f32x4 __attribute__((ext_vector_type(4)));

__device__ __forceinline__ int rfl(int v) { return __builtin_amdgcn_readfirstlane(v); }
__device__ __forceinline__ float rflf(float v) {
  return __uint_as_float(__builtin_amdgcn_readfirstlane(__float_as_uint(v)));
}

// ---- edge dtype detection: int64 edge_index has all-zero high words ----
__global__ void k_detect(const unsigned int* ei, int E, int* flag) {
  int lane = threadIdx.x & 63;
  int n = (E < 64) ? E : 64;
  unsigned int hi = (lane < n) ? ei[2 * lane + 1] : 0u;
  unsigned long long nz = __ballot(hi != 0u);
  if (lane == 0) *flag = (nz == 0ull) ? 1 : 0;
}

// ---- weights fp32 -> fp16 (both layers at once) for the MFMA gemv ----
__global__ void k_wconv(const float* __restrict__ Wl, const float* __restrict__ Wr,
                        __half* __restrict__ Wl16, __half* __restrict__ Wr16,
                        int count) {
  int i = blockIdx.x * blockDim.x + threadIdx.x;
  if (i < count) {
    Wl16[i] = __float2half(Wl[i]);
    Wr16[i] = __float2half(Wr[i]);
  }
}

// ==== CSR build via multisplit (write-local, no global atomics) ====
// Round-7: atomic scatter was write-amplification-bound (107MB HBM writes
// for a 6.4MB array). Round-8 fusion (offsets/inv_deg derived inside
// k_binscatter) measured ~60us cheaper than the k_hist+scan chain — keep.

// pass 0: count matrix C[bucket][block]
__global__ __launch_bounds__(256) void k_bincount(const void* ei, int E,
                                                  const int* __restrict__ flag,
                                                  int* __restrict__ Cmat, int nbuck) {
  __shared__ int lh[MAXBUCK];
  const int is64 = *flag;
  int t = threadIdx.x, j = blockIdx.x;
  for (int b = t; b < nbuck; b += 256) lh[b] = 0;
  __syncthreads();
  int chunk = (E + gridDim.x - 1) / gridDim.x;
  int e0 = j * chunk, e1 = (e0 + chunk < E) ? (e0 + chunk) : E;
  for (int e = e0 + t; e < e1; e += 256) {
    int d = is64 ? (int)((const long long*)ei)[E + e] : ((const int*)ei)[E + e];
    atomicAdd(&lh[d >> BKT_SHIFT], 1);
  }
  __syncthreads();
  for (int b = t; b < nbuck; b += 256) Cmat[b * gridDim.x + j] = lh[b];
}

// exclusive scan of Cmat (bucket-major): scanned values ARE absolute ebuf
// cursors, and Cmat[b*NBLK] is bucket b's base in ebuf.
__global__ void k_scanC(int* __restrict__ C, int len) {
  __shared__ int sm[1024];
  __shared__ int carry;
  int t = threadIdx.x;
  if (t == 0) carry = 0;
  __syncthreads();
  for (int base = 0; base < len; base += 1024) {
    int i = base + t;
    int v = (i < len) ? C[i] : 0;
    sm[t] = v;
    __syncthreads();
    for (int off = 1; off < 1024; off <<= 1) {
      int x = (t >= off) ? sm[t - off] : 0;
      __syncthreads();
      sm[t] += x;
      __syncthreads();
    }
    if (i < len) C[i] = carry + sm[t] - v;  // exclusive
    __syncthreads();
    if (t == 0) carry += sm[1023];
    __syncthreads();
  }
}

// pass 1: write (d,s) packed into ebuf at private per-(block,bucket) cursors
__global__ __launch_bounds__(256) void k_binwrite(const void* ei, int E,
                                                  const int* __restrict__ flag,
                                                  const int* __restrict__ Cmat,
                                                  unsigned long long* __restrict__ ebuf,
                                                  int nbuck) {
  __shared__ int lcur[MAXBUCK];
  const int is64 = *flag;
  int t = threadIdx.x, j = blockIdx.x;
  for (int b = t; b < nbuck; b += 256) lcur[b] = Cmat[b * gridDim.x + j];
  __syncthreads();
  int chunk = (E + gridDim.x - 1) / gridDim.x;
  int e0 = j * chunk, e1 = (e0 + chunk < E) ? (e0 + chunk) : E;
  for (int e = e0 + t; e < e1; e += 256) {
    int s, d;
    if (is64) {
      const long long* p = (const long long*)ei;
      s = (int)p[e];
      d = (int)p[E + e];
    } else {
      const int* p = (const int*)ei;
      s = p[e];
      d = p[E + e];
    }
    int pos = atomicAdd(&lcur[d >> BKT_SHIFT], 1);
    ebuf[pos] = ((unsigned long long)(unsigned)d << 32) | (unsigned)s;
  }
}

// pass 2: one block per bucket. Derives per-node counts from the bucket's
// ebuf slice (LDS histogram), LDS-scans them into offsets/inv_deg, then
// scatters csr within the bucket's contiguous region (single-CU locality).
__global__ __launch_bounds__(256) void k_binscatter(
    const unsigned long long* __restrict__ ebuf, const int* __restrict__ Cs,
    int E, int N, int nbuck, int* __restrict__ offsets,
    float* __restrict__ inv_deg, int* __restrict__ csr) {
  __shared__ int cnt[BSZ];
  __shared__ int sm[256];
  int b = blockIdx.x, t = threadIdx.x;
  int n0 = b << BKT_SHIFT;
  int nn = N - n0;
  if (nn > BSZ) nn = BSZ;
  int p0 = Cs[b * NBLK];
  int p1 = (b + 1 < nbuck) ? Cs[(b + 1) * NBLK] : E;

  for (int i = t; i < BSZ; i += 256) cnt[i] = 0;
  __syncthreads();
  // count per node
  for (int p = p0 + t; p < p1; p += 256) {
    int d = (int)(ebuf[p] >> 32);
    atomicAdd(&cnt[d - n0], 1);
  }
  __syncthreads();
  // exclusive scan of 512 counts: thread t owns pair (2t, 2t+1)
  int c0 = cnt[2 * t], c1 = cnt[2 * t + 1];
  int ps = c0 + c1;
  sm[t] = ps;
  __syncthreads();
  for (int off = 1; off < 256; off <<= 1) {
    int x = (t >= off) ? sm[t - off] : 0;
    __syncthreads();
    sm[t] += x;
    __syncthreads();
  }
  int excl = sm[t] - ps;  // exclusive over pairs
  cnt[2 * t] = excl;
  cnt[2 * t + 1] = excl + c0;
  if (2 * t < nn) {
    offsets[n0 + 2 * t] = p0 + excl;
    inv_deg[n0 + 2 * t] = (c0 > 0) ? (1.0f / (float)c0) : 0.0f;
  }
  if (2 * t + 1 < nn) {
    offsets[n0 + 2 * t + 1] = p0 + excl + c0;
    inv_deg[n0 + 2 * t + 1] = (c1 > 0) ? (1.0f / (float)c1) : 0.0f;
  }
  if (b == nbuck - 1 && t == 0) offsets[N] = E;
  __syncthreads();
  // scatter: cnt[] now holds local exclusive offsets, used as cursors
  for (int p = p0 + t; p < p1; p += 256) {
    unsigned long long pk = ebuf[p];
    int d = (int)(pk >> 32);
    int s = (int)(pk & 0xffffffffull);
    int pos = p0 + atomicAdd(&cnt[d - n0], 1);
    csr[pos] = s;
  }
}

// ---- input projection: h = relu(x @ Wp^T + bp), one wave per node ----
__global__ __launch_bounds__(256) void k_inproj(const float* __restrict__ x,
                                                const float* __restrict__ Wp,
                                                const float* __restrict__ bp,
                                                float* __restrict__ h,
                                                __half* __restrict__ h16, int N) {
  int lane = threadIdx.x & 63;
  int wid = (blockIdx.x * blockDim.x + threadIdx.x) >> 6;
  int nwaves = (gridDim.x * blockDim.x) >> 6;
  float w[FIN];
#pragma unroll
  for (int k = 0; k < FIN; ++k) w[k] = Wp[lane * FIN + k];
  float b = bp[lane];
  for (int n = wid; n < N; n += nwaves) {
    const float4* xr = (const float4*)(x + (size_t)n * FIN);
    float a0 = b, a1 = 0.f;
#pragma unroll
    for (int q = 0; q < FIN / 4; ++q) {
      float4 xv = xr[q];
      a0 = fmaf(xv.x, w[4 * q + 0], a0);
      a1 = fmaf(xv.y, w[4 * q + 1], a1);
      a0 = fmaf(xv.z, w[4 * q + 2], a0);
      a1 = fmaf(xv.w, w[4 * q + 3], a1);
    }
    float r = fmaxf(a0 + a1, 0.0f);
    h[(size_t)n * HH + lane] = r;
    h16[(size_t)n * HH + lane] = __float2half(r);
  }
}

// ---- neighbor-mean gather ONLY: agg16[n] = mean of h16 rows ----
__global__ __launch_bounds__(256, 8) void k_gather(
    const __half* __restrict__ h16_in, const int* __restrict__ offsets,
    const int* __restrict__ csr, const float* __restrict__ inv_deg,
    __half* __restrict__ agg16, int N) {
  int lane = threadIdx.x & 63;
  int wid = (blockIdx.x * blockDim.x + threadIdx.x) >> 6;
  int nwaves = (gridDim.x * blockDim.x) >> 6;
  for (int n = wid; n < N; n += nwaves) {
    int p0 = rfl(offsets[n]);
    int p1 = rfl(offsets[n + 1]);
    float idg = rflf(inv_deg[n]);
    float a0 = 0.f, a1 = 0.f, a2 = 0.f, a3 = 0.f;
    int p = p0;
    for (; p + 16 <= p1; p += 16) {
      float v[16];
#pragma unroll
      for (int i = 0; i < 16; ++i) {
        int s = rfl(csr[p + i]);
        v[i] = __half2float(h16_in[(size_t)s * HH + lane]);
      }
      a0 += (v[0] + v[1]) + (v[2] + v[3]);
      a1 += (v[4] + v[5]) + (v[6] + v[7]);
      a2 += (v[8] + v[9]) + (v[10] + v[11]);
      a3 += (v[12] + v[13]) + (v[14] + v[15]);
    }
    for (; p + 4 <= p1; p += 4) {
      int s0 = rfl(csr[p + 0]), s1 = rfl(csr[p + 1]);
      int s2 = rfl(csr[p + 2]), s3 = rfl(csr[p + 3]);
      float v0 = __half2float(h16_in[(size_t)s0 * HH + lane]);
      float v1 = __half2float(h16_in[(size_t)s1 * HH + lane]);
      float v2 = __half2float(h16_in[(size_t)s2 * HH + lane]);
      float v3 = __half2float(h16_in[(size_t)s3 * HH + lane]);
      a0 += (v0 + v1) + (v2 + v3);
    }
    for (; p < p1; ++p) {
      int s = rfl(csr[p]);
      a0 += __half2float(h16_in[(size_t)s * HH + lane]);
    }
    agg16[(size_t)n * HH + lane] = __float2half(((a0 + a1) + (a2 + a3)) * idg);
  }
}

// ---- MFMA GEMV x2 + LayerNorm + relu + residual, 16 nodes per wave ----
// Round-12: readlane-GEMV was VALU-inst-bound (53% VALUBusy, 2 VALU per FMA,
// memory only 56MB). This IS matmul-shaped (N x 64 @ 64 x 64, K=64) -> MFMA.
// Uses v_mfma_f32_16x16x16f16 (CDNA3-carried; documented layouts:
// A: row=l&15, k=4*(l>>4)+j | B: col=l&15, same k | C/D: col=lane&15,
// row=(lane>>4)*4+reg). Bias seeded into C; both matmuls chain into one acc.
// LN reduces within 16-lane groups (shfl_xor masks 1,2,4,8).
__global__ __launch_bounds__(256) void k_gemv_mfma(
    const float* __restrict__ h_in, const __half* __restrict__ h16_in,
    const __half* __restrict__ agg16,
    float* __restrict__ h_out, __half* __restrict__ h16_out,
    const __half* __restrict__ Wl16, const float* __restrict__ bl,
    const __half* __restrict__ Wr16, const float* __restrict__ gamma,
    const float* __restrict__ beta, int N) {
  int lane = threadIdx.x & 63;
  int wid = (blockIdx.x * blockDim.x + threadIdx.x) >> 6;
  int nwaves = (gridDim.x * blockDim.x) >> 6;
  int c = lane & 15;   // A-load row / D col / B col
  int g = lane >> 4;   // k-block group 0..3 / D row-block

  // j-indexed per-lane constants (tile-independent): j = 16u + c
  float bj[4], gm[4], bt[4];
#pragma unroll
  for (int u = 0; u < 4; ++u) {
    bj[u] = bl[16 * u + c];
    gm[u] = gamma[16 * u + c];
    bt[u] = beta[16 * u + c];
  }

  int ntiles = (N + 15) >> 4;
  for (int tile = wid; tile < ntiles; tile += nwaves) {
    int n0 = tile << 4;
    int rowA = n0 + c;
    if (rowA > N - 1) rowA = N - 1;  // tail clamp (dup rows, stores masked)
    const __half* arow = agg16 + (size_t)rowA * HH + 4 * g;
    const __half* hrow = h16_in + (size_t)rowA * HH + 4 * g;

    half4v aA[4], aH[4];
#pragma unroll
    for (int t = 0; t < 4; ++t) {
      aA[t] = *(const half4v*)(arow + 16 * t);
      aH[t] = *(const half4v*)(hrow + 16 * t);
    }

    f32x4 acc[4];
#pragma unroll
    for (int u = 0; u < 4; ++u) {
      acc[u] = (f32x4){bj[u], bj[u], bj[u], bj[u]};  // bias: same for all rows
#pragma unroll
      for (int t = 0; t < 4; ++t) {
        half4v bL = *(const half4v*)(Wl16 + (size_t)(16 * u + c) * HH + 16 * t + 4 * g);
        half4v bR = *(const half4v*)(Wr16 + (size_t)(16 * u + c) * HH + 16 * t + 4 * g);
        acc[u] = __builtin_amdgcn_mfma_f32_16x16x16f16(aA[t], bL, acc[u], 0, 0, 0);
        acc[u] = __builtin_amdgcn_mfma_f32_16x16x16f16(aH[t], bR, acc[u], 0, 0, 0);
      }
    }

    // LayerNorm: node m = n0 + 4*g + r; its 64 feats live in the 16 lanes of
    // group g, regs (u, r). Reduce across u then across the 16-lane group.
    float mu[4], rs[4];
#pragma unroll
    for (int r = 0; r < 4; ++r) {
      float s = (acc[0][r] + acc[1][r]) + (acc[2][r] + acc[3][r]);
#pragma unroll
      for (int m = 1; m < 16; m <<= 1) s += __shfl_xor(s, m);
      mu[r] = s * (1.0f / 64.0f);
    }
#pragma unroll
    for (int r = 0; r < 4; ++r) {
      float v = 0.f;
#pragma unroll
      for (int u = 0; u < 4; ++u) {
        float d = acc[u][r] - mu[r];
        v += d * d;
      }
#pragma unroll
      for (int m = 1; m < 16; m <<= 1) v += __shfl_xor(v, m);
      rs[r] = rsqrtf(v * (1.0f / 64.0f) + LN_EPS);
    }

#pragma unroll
    for (int u = 0; u < 4; ++u) {
#pragma unroll
      for (int r = 0; r < 4; ++r) {
        int node = n0 + 4 * g + r;
        int nl = (node < N) ? node : N - 1;
        float val = fmaf((acc[u][r] - mu[r]) * rs[r], gm[u], bt[u]);
        float res = fmaxf(val, 0.0f) + h_in[(size_t)nl * HH + 16 * u + c];
        if (node < N) {
          h_out[(size_t)node * HH + 16 * u + c] = res;
          h16_out[(size_t)node * HH + 16 * u + c] = __float2half(res);
        }
      }
    }
  }
}

// ---- MLP head: y = relu(h@W1^T + b1) @ W2^T + b2 ; 2 nodes per wave ----
__global__ __launch_bounds__(256) void k_mlp(const float* __restrict__ h,
                                             const float* __restrict__ W1,
                                             const float* __restrict__ b1,
                                             const float* __restrict__ W2,
                                             const float* __restrict__ b2,
                                             float* __restrict__ y, int N) {
  int lane = threadIdx.x & 63;
  int half = lane >> 5;
  int j = lane & 31;
  int wid = (blockIdx.x * blockDim.x + threadIdx.x) >> 6;
  int nwaves = (gridDim.x * blockDim.x) >> 6;

  float w1[HH];
#pragma unroll
  for (int k = 0; k < HH; ++k) w1[k] = W1[j * HH + k];
  float b1v = b1[j], w2v = W2[j], b2v = b2[0];

  for (int base = wid * 2; base < N; base += nwaves * 2) {
    int n = base + half;
    float t0 = b1v, t1 = 0.0f;
    if (n < N) {
      const float4* hr = (const float4*)(h + (size_t)n * HH);
#pragma unroll
      for (int q = 0; q < HH / 4; ++q) {
        float4 hv = hr[q];
        t0 = fmaf(hv.x, w1[4 * q + 0], t0);
        t1 = fmaf(hv.y, w1[4 * q + 1], t1);
        t0 = fmaf(hv.z, w1[4 * q + 2], t0);
        t1 = fmaf(hv.w, w1[4 * q + 3], t1);
      }
    }
    float t = fmaxf(t0 + t1, 0.0f) * w2v;
#pragma unroll
    for (int m = 1; m < 32; m <<= 1) t += __shfl_xor(t, m);  // stays in half
    if (j == 0 && n < N) y[n] = t + b2v;
  }
}

extern "C" void kernel_launch(void* const* d_in, const int* in_sizes, int n_in,
                              void* d_out, int out_size, void* d_ws, size_t ws_size,
                              hipStream_t stream) {
  const float* x = (const float*)d_in[0];
  const void* ei = d_in[1];
  const float* Wp = (const float*)d_in[2];
  const float* bp = (const float*)d_in[3];
  const float* Wl = (const float*)d_in[4];
  const float* bl = (const float*)d_in[5];
  const float* Wr = (const float*)d_in[6];
  const float* gamma = (const float*)d_in[7];
  const float* beta = (const float*)d_in[8];
  const float* W1 = (const float*)d_in[9];
  const float* b1 = (const float*)d_in[10];
  const float* W2 = (const float*)d_in[11];
  const float* b2 = (const float*)d_in[12];
  float* y = (float*)d_out;

  const int N = in_sizes[0] / FIN;
  const int E = in_sizes[1] / 2;
  const int nbuck = (N + BSZ - 1) >> BKT_SHIFT;  // <= MAXBUCK

  // workspace carve (256B aligned chunks)
  char* w = (char*)d_ws;
  auto carve = [&](size_t bytes) -> char* {
    char* p = w;
    w += (bytes + 255) / 256 * 256;
    return p;
  };
  int* offsets = (int*)carve(((size_t)N + 1) * 4);
  int* flag = (int*)carve(4);
  float* invdeg = (float*)carve((size_t)N * 4);
  int* csr = (int*)carve((size_t)E * 4);
  int* Cmat = (int*)carve((size_t)MAXBUCK * NBLK * 4);
  unsigned long long* ebuf = (unsigned long long*)carve((size_t)E * 8);
  float* hA = (float*)carve((size_t)N * HH * 4);
  float* hB = (float*)carve((size_t)N * HH * 4);
  __half* h16A = (__half*)carve((size_t)N * HH * 2);
  __half* h16B = (__half*)carve((size_t)N * HH * 2);
  __half* agg16 = (__half*)carve((size_t)N * HH * 2);  // reused both layers
  __half* Wl16 = (__half*)carve((size_t)2 * HH * HH * 2);
  __half* Wr16 = (__half*)carve((size_t)2 * HH * HH * 2);

  k_detect<<<1, 64, 0, stream>>>((const unsigned int*)ei, E, flag);
  k_wconv<<<32, 256, 0, stream>>>(Wl, Wr, Wl16, Wr16, 2 * HH * HH);
  // CSR build: multisplit; binscatter also derives offsets/inv_deg
  k_bincount<<<NBLK, 256, 0, stream>>>(ei, E, flag, Cmat, nbuck);
  k_scanC<<<1, 1024, 0, stream>>>(Cmat, nbuck * NBLK);
  k_binwrite<<<NBLK, 256, 0, stream>>>(ei, E, flag, Cmat, ebuf, nbuck);
  k_binscatter<<<nbuck, 256, 0, stream>>>(ebuf, Cmat, E, N, nbuck,
                                          offsets, invdeg, csr);
  k_inproj<<<1024, 256, 0, stream>>>(x, Wp, bp, hA, h16A, N);
  // layer 0
  k_gather<<<2048, 256, 0, stream>>>(h16A, offsets, csr, invdeg, agg16, N);
  k_gemv_mfma<<<1024, 256, 0, stream>>>(hA, h16A, agg16, hB, h16B,
                                        Wl16, bl, Wr16, gamma, beta, N);
  // layer 1
  k_gather<<<2048, 256, 0, stream>>>(h16B, offsets, csr, invdeg, agg16, N);
  k_gemv_mfma<<<1024, 256, 0, stream>>>(hB, h16B, agg16, hA, h16A,
                                        Wl16 + HH * HH, bl + HH, Wr16 + HH * HH,
                                        gamma + HH, beta + HH, N);
  k_mlp<<<512, 256, 0, stream>>>(hA, W1, b1, W2, b2, y, N);
}